// Round 8
// baseline (440.195 us; speedup 1.0000x reference)
//
#include <hip/hip_runtime.h>
#include <hip/hip_bf16.h>
#include <math.h>

#define NTOK   65536
#define L_SEQ  16384

typedef __bf16 bf16_t;
typedef bf16_t bf16x8 __attribute__((ext_vector_type(8)));
typedef bf16_t bf16x4 __attribute__((ext_vector_type(4)));
typedef float  f32x4  __attribute__((ext_vector_type(4)));

__device__ inline float phi_f(float x) { return x > 0.f ? x + 1.f : __expf(x); }

__device__ inline float quad_sum(float v) {
    v += __shfl_xor(v, 1);
    v += __shfl_xor(v, 2);
    v += __shfl_xor(v, 4);
    v += __shfl_xor(v, 8);
    return v;
}

__device__ inline float ld_any(const void* p, size_t i, int f32) {
    return f32 ? ((const float*)p)[i] : (float)((const bf16_t*)p)[i];
}

// async 16B global->LDS (direct-to-shared DMA; HW dest = wave-uniform base +
// lane*16 — callers below always pass lds ptrs of exactly that shape)
__device__ inline void async_copy16(const bf16_t* g, bf16_t* l) {
    __builtin_amdgcn_global_load_lds(
        (const __attribute__((address_space(1))) unsigned int*)g,
        (__attribute__((address_space(3))) unsigned int*)l, 16, 0, 0);
}

// Stage nslot 16-B units (8 bf16 each; nslot = elements/8) of a
// [rows][rowstride] bf16 slice into LDS with an XOR swizzle of the
// (1<<ulog2) units per row: phys j = u ^ (n & (U-1)).
__device__ inline void stage_swz(const bf16_t* __restrict__ g, bf16_t* lds,
                                 int tid, int nslot, int ulog2, int rowstride) {
    const int umask = (1 << ulog2) - 1;
    for (int s = tid; s < nslot; s += 256) {
        int n = s >> ulog2, j = s & umask;
        int u = j ^ (n & umask);
        async_copy16(g + (size_t)n * rowstride + u * 8, lds + (size_t)s * 8);
    }
}

__device__ inline bf16x8 rd_swz(const bf16_t* lds, int n, int u, int ulog2) {
    int j = u ^ (n & ((1 << ulog2) - 1));
    return *(const bf16x8*)&lds[(((size_t)n << ulog2) + j) * 8];
}

// ---- W2 chunk [256 n][32 k] packed as [128 rows][64 cols] so LDS rows span
// 128B = all 32 banks. Row r = n&127, slot u = (n>>7)*4 + k/8, phys = u^(r&7).
// Verified conflict-free in round 5.
__device__ inline void stage_w2ff(const bf16_t* __restrict__ W2_t, int ch,
                                  bf16_t* lds, int tid) {
    for (int S = tid; S < 1024; S += 256) {
        int r = S >> 3, phys = S & 7;
        int u = phys ^ (r & 7);
        int n = ((u >> 2) << 7) + r;
        int ks = u & 3;
        async_copy16(W2_t + (size_t)n * 1024 + ch * 32 + ks * 8, lds + (size_t)S * 8);
    }
}

__device__ inline bf16x8 rd_w2ff(const bf16_t* lds, int n, int quad) {
    int r = n & 127;
    int u = ((n >> 7) << 2) + quad;
    int phys = u ^ (r & 7);
    return *(const bf16x8*)&lds[(size_t)(r * 8 + phys) * 8];
}

// ---- [32 dim][128 tok] bf16 tile with 16B-unit XOR swizzle:
// element (r,c): unit u = c>>3, phys = u ^ (r&15), idx = r*128 + phys*8 + (c&7).
// Read of 8 contiguous c within one unit -> bf16x8; 16 lanes (distinct r&15)
// spread across banks (2-way = free).
__device__ inline void hs_put(bf16_t* hs, int r, int c, bf16_t v) {
    int phys = (c >> 3) ^ (r & 15);
    hs[r * 128 + phys * 8 + (c & 7)] = v;
}
__device__ inline bf16x8 hs_get8(const bf16_t* hs, int r, int u) {
    int phys = u ^ (r & 15);
    return *(const bf16x8*)&hs[r * 128 + phys * 8];
}

// A-frags for one wave: row m, k = kk*32 + quad*8, kk=0..7 (K=256)
__device__ inline void ld_afrags(const bf16_t* __restrict__ tile, int row, int q8,
                                 bf16x8 a[8]) {
#pragma unroll
    for (int kk = 0; kk < 8; ++kk)
        a[kk] = *(const bf16x8*)&tile[(size_t)row * 256 + kk * 32 + q8];
}

// ------------------------------------------------- K-1: dtype probe
__global__ __launch_bounds__(256) void k_detect(const void* __restrict__ xraw,
                                                int* __restrict__ flag) {
    __shared__ int bad;
    if (threadIdx.x == 0) bad = 0;
    __syncthreads();
    const bf16_t* xb = (const bf16_t*)xraw;
    int mybad = 0;
#pragma unroll
    for (int j = 0; j < 16; ++j) {
        float v = fabsf((float)xb[threadIdx.x + 256 * j]);
        if (!(v <= 1000.f)) mybad = 1;
    }
    if (mybad) atomicOr(&bad, 1);
    __syncthreads();
    if (threadIdx.x == 0) *flag = bad;
}

// ------------------------------------------------- K0a: x -> canonical bf16
__global__ __launch_bounds__(256) void k_convert(const void* __restrict__ xraw,
                                                 const int* __restrict__ flag,
                                                 bf16_t* __restrict__ xbf) {
    const int f = *flag;
    size_t i = ((size_t)blockIdx.x * 256 + threadIdx.x) * 4;
    if (f) {
        f32x4 v = *(const f32x4*)((const float*)xraw + i);
        bf16x4 o;
#pragma unroll
        for (int j = 0; j < 4; ++j) o[j] = (bf16_t)v[j];
        *(bf16x4*)&xbf[i] = o;
    } else {
        *(bf16x4*)&xbf[i] = *(const bf16x4*)((const bf16_t*)xraw + i);
    }
}

// ------------------------------------------------- K0b: weight transpose + bias pack
__global__ __launch_bounds__(256) void k_prep(
    const void* __restrict__ Wq, const void* __restrict__ Wk,
    const void* __restrict__ Wv, const void* __restrict__ Wo,
    const void* __restrict__ W1, const void* __restrict__ W2,
    const void* __restrict__ bq, const void* __restrict__ bk,
    const void* __restrict__ bv, const void* __restrict__ bo,
    const void* __restrict__ b1, const void* __restrict__ b2,
    const void* __restrict__ g1, const void* __restrict__ be1,
    const void* __restrict__ g2, const void* __restrict__ be2,
    const int* __restrict__ flag,
    bf16_t* __restrict__ Wqkv_t, bf16_t* __restrict__ Wo_t,
    bf16_t* __restrict__ W1_t, bf16_t* __restrict__ W2_t,
    bf16_t* __restrict__ pbuf, float* __restrict__ kvbuf) {
    const int f = *flag;
    int idx = blockIdx.x * 256 + threadIdx.x;
    if (idx < 196608) {                       // Wqkv_t [768][256]
        int n = idx >> 8, k = idx & 255;
        float v;
        if (n < 256)      v = ld_any(Wq, k * 256 + n, f);
        else if (n < 512) v = ld_any(Wk, k * 256 + (n - 256), f);
        else              v = ld_any(Wv, k * 256 + (n - 512), f);
        Wqkv_t[idx] = (bf16_t)v;
    } else if (idx < 262144) {                // Wo_t [256][256]
        int i = idx - 196608; int n = i >> 8, k = i & 255;
        Wo_t[i] = (bf16_t)ld_any(Wo, k * 256 + n, f);
    } else if (idx < 524288) {                // W1_t [1024][256]
        int i = idx - 262144; int n = i >> 8, k = i & 255;
        W1_t[i] = (bf16_t)ld_any(W1, k * 1024 + n, f);
    } else if (idx < 786432) {                // W2_t [256][1024]
        int i = idx - 524288; int n = i >> 10, k = i & 1023;
        W2_t[i] = (bf16_t)ld_any(W2, k * 256 + n, f);
    } else if (idx < 820224) {                // KV state zero-init
        kvbuf[idx - 786432] = 0.f;
    } else if (idx < 823552) {                // bias/param pack
        int i = idx - 820224;
        float v;
        if (i < 256)        v = ld_any(bq, i, f);
        else if (i < 512)   v = ld_any(bk, i - 256, f);
        else if (i < 768)   v = ld_any(bv, i - 512, f);
        else if (i < 1024)  v = ld_any(bo, i - 768, f);
        else if (i < 2048)  v = ld_any(b1, i - 1024, f);
        else if (i < 2304)  v = ld_any(b2, i - 2048, f);
        else if (i < 2560)  v = ld_any(g1, i - 2304, f);
        else if (i < 2816)  v = ld_any(be1, i - 2560, f);
        else if (i < 3072)  v = ld_any(g2, i - 2816, f);
        else                v = ld_any(be2, i - 3072, f);
        pbuf[i] = (bf16_t)v;
    }
}

// ------------------------------------------------- K1: Q GEMM + phi (Q only)
// Round 8: K/V columns moved to k_kv (fused with kv reduction); this kernel
// now only computes Q_phi. grid (512, 2): M=128, N=128 per block.
__global__ __launch_bounds__(256, 3) void k_qkv(
    const bf16_t* __restrict__ x, const bf16_t* __restrict__ Wqkv_t,
    const bf16_t* __restrict__ pbuf, bf16_t* __restrict__ q_phi) {
    const int mt = blockIdx.x, nt = blockIdx.y;
    const int tid = threadIdx.x, wave = tid >> 6, lane = tid & 63;
    const int l15 = lane & 15, quad = lane >> 4, q8 = quad * 8;
    __shared__ __align__(16) bf16_t bs[128 * 256];
    const int m0 = mt * 128;
    bf16x8 a[2][8];
    ld_afrags(x + (size_t)m0 * 256,        wave * 16 + l15, q8, a[0]);
    ld_afrags(x + (size_t)(m0 + 64) * 256, wave * 16 + l15, q8, a[1]);
    stage_swz(Wqkv_t + (size_t)nt * 128 * 256, bs, tid, 4096, 5, 256);
    __syncthreads();
    f32x4 acc[2][8] = {};
#pragma unroll
    for (int kk = 0; kk < 8; ++kk) {
#pragma unroll
        for (int s = 0; s < 8; ++s) {
            bf16x8 b = rd_swz(bs, s * 16 + l15, kk * 4 + quad, 5);
            acc[0][s] = __builtin_amdgcn_mfma_f32_16x16x32_bf16(a[0][kk], b, acc[0][s], 0, 0, 0);
            acc[1][s] = __builtin_amdgcn_mfma_f32_16x16x32_bf16(a[1][kk], b, acc[1][s], 0, 0, 0);
        }
    }
#pragma unroll
    for (int s = 0; s < 8; ++s) {
        int ng = nt * 128 + s * 16 + l15;      // 0..255: always Q
        float bias = (float)pbuf[ng];
#pragma unroll
        for (int mm = 0; mm < 2; ++mm) {
#pragma unroll
            for (int r = 0; r < 4; ++r) {
                int m = m0 + mm * 64 + wave * 16 + quad * 4 + r;
                q_phi[(size_t)m * 256 + ng] = (bf16_t)phi_f(acc[mm][s][r] + bias);
            }
        }
    }
}

// ------------------------------------------------- K2 (new): fused K/V + kv state
// grid (512, 2): mt = 128-token slab, hg = head group (hg*4 .. hg*4+3).
// Per head: stage Wk head cols (16KB) -> K_phi GEMM -> ksum partial atomics ->
// scatter transposed [d][tok] into hsK; same for V -> hsV; then kv[d][e] +=
// K_phi^T @ V via 4 MFMAs/wave (contraction over the slab's 128 tokens),
// atomicAdd into kvbuf. K_phi / V never touch HBM (saves 128MB round-trip +
// the whole old k_kvsum kernel). LDS 32KB -> 4 blocks/CU, barriers hidden.
__global__ __launch_bounds__(256, 4) void k_kv(
    const bf16_t* __restrict__ x, const bf16_t* __restrict__ Wqkv_t,
    const bf16_t* __restrict__ pbuf, float* __restrict__ kvbuf) {
    const int mt = blockIdx.x, hg = blockIdx.y;
    const int tid = threadIdx.x, wave = tid >> 6, lane = tid & 63;
    const int l15 = lane & 15, quad = lane >> 4, q8 = quad * 8;
    __shared__ __align__(16) bf16_t stg[8192];     // 32 cols x 256 K staging
    __shared__ __align__(16) bf16_t hsK[4096];     // [32 d][128 tok] swizzled
    __shared__ __align__(16) bf16_t hsV[4096];     // [32 e][128 tok] swizzled
    const int m0 = mt * 128;
    const int b = m0 >> 14;
    bf16x8 a[2][8];
    ld_afrags(x + (size_t)m0 * 256,        wave * 16 + l15, q8, a[0]);
    ld_afrags(x + (size_t)(m0 + 64) * 256, wave * 16 + l15, q8, a[1]);
    const int td = wave >> 1, te = wave & 1;       // this wave's kv 16x16 tile
    for (int h4 = 0; h4 < 4; ++h4) {
        const int head = hg * 4 + h4;
        const size_t kvbase = (size_t)(b * 8 + head) * 1056;
        // ---------------- K phase ----------------
        stage_swz(Wqkv_t + (size_t)(256 + head * 32) * 256, stg, tid, 1024, 5, 256);
        __syncthreads();                            // stg ready; hsK/V free
        {
            f32x4 acck[2][2] = {};
#pragma unroll
            for (int kk = 0; kk < 8; ++kk) {
#pragma unroll
                for (int s = 0; s < 2; ++s) {
                    bf16x8 bb = rd_swz(stg, s * 16 + l15, kk * 4 + quad, 5);
                    acck[0][s] = __builtin_amdgcn_mfma_f32_16x16x32_bf16(a[0][kk], bb, acck[0][s], 0, 0, 0);
                    acck[1][s] = __builtin_amdgcn_mfma_f32_16x16x32_bf16(a[1][kk], bb, acck[1][s], 0, 0, 0);
                }
            }
#pragma unroll
            for (int s = 0; s < 2; ++s) {
                float bias = (float)pbuf[256 + head * 32 + s * 16 + l15];
                float kst = 0.f;
#pragma unroll
                for (int mm = 0; mm < 2; ++mm) {
#pragma unroll
                    for (int r = 0; r < 4; ++r) {
                        float v = phi_f(acck[mm][s][r] + bias);
                        kst += v;
                        int c = mm * 64 + wave * 16 + quad * 4 + r;   // token idx
                        hs_put(hsK, s * 16 + l15, c, (bf16_t)v);
                    }
                }
                kst += __shfl_xor(kst, 16);          // sum across quads
                kst += __shfl_xor(kst, 32);
                if (quad == 0)
                    atomicAdd(&kvbuf[kvbase + 1024 + s * 16 + l15], kst);
            }
        }
        __syncthreads();                            // stg(K) fully consumed
        // ---------------- V phase ----------------
        stage_swz(Wqkv_t + (size_t)(512 + head * 32) * 256, stg, tid, 1024, 5, 256);
        __syncthreads();                            // stg ready
        {
            f32x4 accv[2][2] = {};
#pragma unroll
            for (int kk = 0; kk < 8; ++kk) {
#pragma unroll
                for (int s = 0; s < 2; ++s) {
                    bf16x8 bb = rd_swz(stg, s * 16 + l15, kk * 4 + quad, 5);
                    accv[0][s] = __builtin_amdgcn_mfma_f32_16x16x32_bf16(a[0][kk], bb, accv[0][s], 0, 0, 0);
                    accv[1][s] = __builtin_amdgcn_mfma_f32_16x16x32_bf16(a[1][kk], bb, accv[1][s], 0, 0, 0);
                }
            }
#pragma unroll
            for (int s = 0; s < 2; ++s) {
                float bias = (float)pbuf[512 + head * 32 + s * 16 + l15];
#pragma unroll
                for (int mm = 0; mm < 2; ++mm) {
#pragma unroll
                    for (int r = 0; r < 4; ++r) {
                        int c = mm * 64 + wave * 16 + quad * 4 + r;   // token idx
                        hs_put(hsV, s * 16 + l15, c, (bf16_t)(accv[mm][s][r] + bias));
                    }
                }
            }
        }
        __syncthreads();                            // hsK + hsV complete
        // ---------------- kv contraction: D[d][e] = sum_tok K^T V ----------------
        {
            f32x4 kvacc = {};
#pragma unroll
            for (int kk = 0; kk < 4; ++kk) {        // K = 128 tokens
                bf16x8 ak = hs_get8(hsK, td * 16 + l15, kk * 4 + quad);
                bf16x8 bv = hs_get8(hsV, te * 16 + l15, kk * 4 + quad);
                kvacc = __builtin_amdgcn_mfma_f32_16x16x32_bf16(ak, bv, kvacc, 0, 0, 0);
            }
#pragma unroll
            for (int r = 0; r < 4; ++r) {           // C-layout: row=quad*4+r, col=l15
                int d = td * 16 + quad * 4 + r;
                int e = te * 16 + l15;
                atomicAdd(&kvbuf[kvbase + e * 32 + d], kvacc[r]);
            }
        }
        // next head's first __syncthreads orders kv reads vs hsK/hsV overwrite
    }
}

// ------------------------------------------------- K2b: kv f32 -> bf16 pack
// kvbf[bh*1024 + e*32 + d] = (bf16) kvbuf[bh*1056 + e*32 + d]
__global__ __launch_bounds__(256) void k_kvprep(const float* __restrict__ kvbuf,
                                                bf16_t* __restrict__ kvbf) {
    int idx = blockIdx.x * 256 + threadIdx.x;       // 8192 total
    int bh = idx >> 8, r4 = (idx & 255) * 4;
    f32x4 v = *(const f32x4*)&kvbuf[(size_t)bh * 1056 + r4];
    bf16x4 o;
#pragma unroll
    for (int j = 0; j < 4; ++j) o[j] = (bf16_t)v[j];
    *(bf16x4*)&kvbf[(size_t)bh * 1024 + r4] = o;
}

// ------------------------------------------------- K3+K4 fused: attention
// apply (q_phi @ kv * z) + @Wo + x residual + LN1. M=128 per block.
__global__ __launch_bounds__(256, 2) void k_attn_wo_ln1(
    const bf16_t* __restrict__ q_phi, const bf16_t* __restrict__ kvbf,
    const float* __restrict__ kvbuf, const bf16_t* __restrict__ Wo_t,
    const bf16_t* __restrict__ pbuf, const void* __restrict__ xraw,
    const int* __restrict__ flag, bf16_t* __restrict__ x1) {
    const int f = *flag;
    const int mt = blockIdx.x;
    const int tid = threadIdx.x, wave = tid >> 6, lane = tid & 63;
    const int l15 = lane & 15, quad = lane >> 4, q8 = quad * 8;
    __shared__ __align__(16) bf16_t sm0[8192];         // Wo chunk (nc even), 16KB
    __shared__ __align__(16) bf16_t sm1[16896];        // hs, then Wo chunk (nc odd)
    const int m0 = mt * 128;
    const int b = m0 >> 14;                            // batch (128-row blocks never straddle)
    stage_swz(Wo_t, sm0, tid, 1024, 5, 256);           // async chunk0 (32 rows)
    // ---------------- attention phase (wave-local, no barrier) ----------------
    bf16_t* hs = sm1 + wave * (16 * 264);              // [16 rows][264 cols]
    const bf16_t* kvb = kvbf + (size_t)b * 8192;       // 8 heads * 1024 bf16
    const float*  ksb = kvbuf + (size_t)b * 8448;      // 8 heads * 1056 f32
    bf16x8 a2[2][8];
#pragma unroll
    for (int mm = 0; mm < 2; ++mm) {
        bf16x8 a[8];
        ld_afrags(q_phi + (size_t)(m0 + mm * 64) * 256, wave * 16 + l15, q8, a);
#pragma unroll
        for (int h = 0; h < 8; ++h) {
            // denominator: q[m=l15][h*32 + quad*8+j] . ksum
            f32x4 ks0 = *(const f32x4*)&ksb[h * 1056 + 1024 + q8];
            f32x4 ks1 = *(const f32x4*)&ksb[h * 1056 + 1024 + q8 + 4];
            float den = 0.f;
#pragma unroll
            for (int j = 0; j < 4; ++j) den += (float)a[h][j] * ks0[j];
#pragma unroll
            for (int j = 0; j < 4; ++j) den += (float)a[h][4 + j] * ks1[j];
            den += __shfl_xor(den, 16);                // reduce across quads
            den += __shfl_xor(den, 32);
            float z = 1.f / (den + 1e-6f);             // z for row = l15
            float zr[4];
#pragma unroll
            for (int r = 0; r < 4; ++r) zr[r] = __shfl(z, quad * 4 + r, 16);
            // numerator: B[k=d][n=e] = kv[d][e], e-major -> contiguous frag
            bf16x8 b0 = *(const bf16x8*)&kvb[h * 1024 + l15 * 32 + q8];
            bf16x8 b1 = *(const bf16x8*)&kvb[h * 1024 + (16 + l15) * 32 + q8];
            f32x4 at0 = {}, at1 = {};
            at0 = __builtin_amdgcn_mfma_f32_16x16x32_bf16(a[h], b0, at0, 0, 0, 0);
            at1 = __builtin_amdgcn_mfma_f32_16x16x32_bf16(a[h], b1, at1, 0, 0, 0);
#pragma unroll
            for (int r = 0; r < 4; ++r) {              // C-layout: row=quad*4+r, col=l15
                hs[(quad * 4 + r) * 264 + h * 32 + l15]      = (bf16_t)(at0[r] * zr[r]);
                hs[(quad * 4 + r) * 264 + h * 32 + 16 + l15] = (bf16_t)(at1[r] * zr[r]);
            }
        }
        // wave-local C->A layout round-trip (in-order DS pipe within wave)
#pragma unroll
        for (int kk = 0; kk < 8; ++kk)
            a2[mm][kk] = *(const bf16x8*)&hs[l15 * 264 + kk * 32 + q8];
    }
    __syncthreads();       // sm0 chunk0 staged; all waves done with hs (sm1)
    // ---------------- Wo GEMM, 8 chunks of 32 cols, ping-pong sm0/sm1 --------
    f32x4 acc[2][16] = {};
    for (int nc = 0; nc < 8; ++nc) {
        if (nc < 7) stage_swz(Wo_t + (size_t)(nc + 1) * 32 * 256,
                              (nc & 1) ? sm0 : sm1, tid, 1024, 5, 256);
        const bf16_t* buf = (nc & 1) ? sm1 : sm0;
#pragma unroll
        for (int kk = 0; kk < 8; ++kk) {
#pragma unroll
            for (int s = 0; s < 2; ++s) {
                bf16x8 bb = rd_swz(buf, s * 16 + l15, kk * 4 + quad, 5);
                acc[0][nc * 2 + s] = __builtin_amdgcn_mfma_f32_16x16x32_bf16(a2[0][kk], bb, acc[0][nc * 2 + s], 0, 0, 0);
                acc[1][nc * 2 + s] = __builtin_amdgcn_mfma_f32_16x16x32_bf16(a2[1][kk], bb, acc[1][nc * 2 + s], 0, 0, 0);
            }
        }
        __syncthreads();   // publishes next chunk, protects current from overwrite
    }
    // ---------------- epilogue: bias + x residual + LN1 (per m-subtile) ------
#pragma unroll
    for (int mm = 0; mm < 2; ++mm) {
        float s1[4] = {}, s2[4] = {};
#pragma unroll
        for (int s = 0; s < 16; ++s) {
            int n = s * 16 + l15;
            float bias = (float)pbuf[768 + n];
#pragma unroll
            for (int r = 0; r < 4; ++r) {
                int m = m0 + mm * 64 + wave * 16 + quad * 4 + r;
                float val = acc[mm][s][r] + bias + ld_any(xraw, (size_t)m * 256 + n, f);
                acc[mm][s][r] = val;
                s1[r] += val; s2[r] += val * val;
            }
        }
#pragma unroll
        for (int r = 0; r < 4; ++r) {
            float ts = quad_sum(s1[r]), ts2 = quad_sum(s2[r]);
            float mu = ts * (1.f / 256.f);
            float rs = rsqrtf(ts2 * (1.f / 256.f) - mu * mu + 1e-5f);
            s1[r] = mu; s2[r] = rs;
        }
#pragma unroll
        for (int s = 0; s < 16; ++s) {
            int n = s * 16 + l15;
            float gn = (float)pbuf[2304 + n], bn = (float)pbuf[2560 + n];
#pragma unroll
            for (int r = 0; r < 4; ++r) {
                int m = m0 + mm * 64 + wave * 16 + quad * 4 + r;
                x1[(size_t)m * 256 + n] = (bf16_t)((acc[mm][s][r] - s1[r]) * s2[r] * gn + bn);
            }
        }
    }
}

// ------------------------------------------------- K5: fused FFN + LN2
// M=128 per block (512 blocks), double-buffer + 1 barrier/chunk, conflict-free
// w2ff pack. (Round-6 verified: ~115us, LDS-BW-bound.) Unchanged.
__global__ __launch_bounds__(256, 2) void k_ff_ln2(
    const bf16_t* __restrict__ x1, const bf16_t* __restrict__ W1_t,
    const bf16_t* __restrict__ W2_t, const bf16_t* __restrict__ pbuf,
    const int* __restrict__ flag, void* __restrict__ out) {
    const int f32o = *flag;
    const int mt = blockIdx.x;                        // 512 blocks, 128 rows each
    const int tid = threadIdx.x, wave = tid >> 6, lane = tid & 63;
    const int l15 = lane & 15, quad = lane >> 4, q8 = quad * 8;
    __shared__ __align__(16) bf16_t w1s[2][8192];     // 32 ff-rows x 256 K each
    __shared__ __align__(16) bf16_t w2s[2][8192];     // [128][64] packed chunk
    __shared__ __align__(16) bf16_t hs[4][2][16][40]; // wave x m-subtile h buf
    const int m0 = mt * 128 + wave * 32;              // wave's first row
    bf16x8 a[2][8];
    ld_afrags(x1 + (size_t)m0 * 256, l15,      q8, a[0]);
    ld_afrags(x1 + (size_t)m0 * 256, 16 + l15, q8, a[1]);
    stage_swz(W1_t, w1s[0], tid, 1024, 5, 256);
    stage_w2ff(W2_t, 0, w2s[0], tid);
    __syncthreads();
    f32x4 acc[2][16] = {};
    for (int ch = 0; ch < 32; ++ch) {
        const int cur = ch & 1;
        // prefetch next chunk into the idle buffers (latency hides under MFMAs)
        if (ch < 31) {
            stage_swz(W1_t + (size_t)(ch + 1) * 32 * 256, w1s[cur ^ 1], tid, 1024, 5, 256);
            stage_w2ff(W2_t, ch + 1, w2s[cur ^ 1], tid);
        }
        // step a: h = relu(x1 @ W1_chunk + b1), 32 ff-cols, 2 m-subtiles
        f32x4 h0[2] = {}, h1[2] = {};
#pragma unroll
        for (int kk = 0; kk < 8; ++kk) {
#pragma unroll
            for (int s = 0; s < 2; ++s) {
                bf16x8 b = rd_swz(w1s[cur], s * 16 + l15, kk * 4 + quad, 5);
                h0[s] = __builtin_amdgcn_mfma_f32_16x16x32_bf16(a[0][kk], b, h0[s], 0, 0, 0);
                h1[s] = __builtin_amdgcn_mfma_f32_16x16x32_bf16(a[1][kk], b, h1[s], 0, 0, 0);
            }
        }
#pragma unroll
        for (int s = 0; s < 2; ++s) {
            float bias = (float)pbuf[1024 + ch * 32 + s * 16 + l15];
#pragma unroll
            for (int r = 0; r < 4; ++r) {
                float v0 = h0[s][r] + bias;
                float v1 = h1[s][r] + bias;
                hs[wave][0][quad * 4 + r][s * 16 + l15] = (bf16_t)(v0 > 0.f ? v0 : 0.f);
                hs[wave][1][quad * 4 + r][s * 16 + l15] = (bf16_t)(v1 > 0.f ? v1 : 0.f);
            }
        }
        // wave-local C->A layout round-trip (in-order DS pipe within wave)
        bf16x8 a2_0 = *(const bf16x8*)&hs[wave][0][l15][q8];
        bf16x8 a2_1 = *(const bf16x8*)&hs[wave][1][l15][q8];
        // step b: out += h_chunk @ W2_chunk (B-frag shared across m-subtiles)
#pragma unroll
        for (int s = 0; s < 16; ++s) {
            bf16x8 b0 = rd_w2ff(w2s[cur], s * 16 + l15, quad);
            acc[0][s] = __builtin_amdgcn_mfma_f32_16x16x32_bf16(a2_0, b0, acc[0][s], 0, 0, 0);
            acc[1][s] = __builtin_amdgcn_mfma_f32_16x16x32_bf16(a2_1, b0, acc[1][s], 0, 0, 0);
        }
        __syncthreads();   // next-chunk stages complete; cur buffers reusable
    }
    // epilogue: + b2 + x1 residual, LN2, dual-dtype store (per m-subtile)
#pragma unroll
    for (int mm = 0; mm < 2; ++mm) {
        float s1[4] = {}, s2[4] = {};
#pragma unroll
        for (int s = 0; s < 16; ++s) {
            int n = s * 16 + l15;
            float bias = (float)pbuf[2048 + n];
#pragma unroll
            for (int r = 0; r < 4; ++r) {
                int m = m0 + mm * 16 + quad * 4 + r;
                float val = acc[mm][s][r] + bias + (float)x1[(size_t)m * 256 + n];
                acc[mm][s][r] = val;
                s1[r] += val; s2[r] += val * val;
            }
        }
#pragma unroll
        for (int r = 0; r < 4; ++r) {
            float ts = quad_sum(s1[r]), ts2 = quad_sum(s2[r]);
            float mu = ts * (1.f / 256.f);
            float rs = rsqrtf(ts2 * (1.f / 256.f) - mu * mu + 1e-5f);
            s1[r] = mu; s2[r] = rs;
        }
#pragma unroll
        for (int s = 0; s < 16; ++s) {
            int n = s * 16 + l15;
            float gn = (float)pbuf[2816 + n], bn = (float)pbuf[3072 + n];
#pragma unroll
            for (int r = 0; r < 4; ++r) {
                int m = m0 + mm * 16 + quad * 4 + r;
                float val = (acc[mm][s][r] - s1[r]) * s2[r] * gn + bn;
                if (f32o) ((float*)out)[(size_t)m * 256 + n] = val;
                else      ((bf16_t*)out)[(size_t)m * 256 + n] = (bf16_t)val;
            }
        }
    }
}

// ------------------------------------------------- launch
extern "C" void kernel_launch(void* const* d_in, const int* in_sizes, int n_in,
                              void* d_out, int out_size, void* d_ws, size_t ws_size,
                              hipStream_t stream) {
    char* ws = (char*)d_ws;
    int*    flag   = (int*)ws;                              // 4 B (256 reserved)
    bf16_t* xbf    = (bf16_t*)(ws + 256);                   // 16.7M elems
    bf16_t* Wqkv_t = (bf16_t*)(ws + 33554688);              // 196608
    bf16_t* Wo_t   = (bf16_t*)(ws + 33947904);              // 65536
    bf16_t* W1_t   = (bf16_t*)(ws + 34078976);              // 262144
    bf16_t* W2_t   = (bf16_t*)(ws + 34603264);              // 262144
    bf16_t* pbuf   = (bf16_t*)(ws + 35127552);              // 3328
    float*  kvbuf  = (float*)(ws + 35134208);               // 33792 f32
    bf16_t* bufQ   = (bf16_t*)(ws + 35269376);              // 16.7M elems
    bf16_t* kvbf   = bufQ + (size_t)NTOK * 256;             // 64KB (old bufK slot)
    bf16_t* bufX1  = bufQ;    // Q read + overwritten row-local in k_attn_wo_ln1

    k_detect<<<1, 256, 0, stream>>>(d_in[0], flag);
    k_convert<<<16384, 256, 0, stream>>>(d_in[0], flag, xbf);
    k_prep<<<3217, 256, 0, stream>>>(d_in[1], d_in[3], d_in[5], d_in[7],
                                     d_in[9], d_in[11],
                                     d_in[2], d_in[4], d_in[6], d_in[8],
                                     d_in[10], d_in[12],
                                     d_in[13], d_in[14], d_in[15], d_in[16],
                                     flag, Wqkv_t, Wo_t, W1_t, W2_t, pbuf, kvbuf);
    k_qkv<<<dim3(512, 2), 256, 0, stream>>>(xbf, Wqkv_t, pbuf, bufQ);
    k_kv<<<dim3(512, 2), 256, 0, stream>>>(xbf, Wqkv_t, pbuf, kvbuf);
    k_kvprep<<<32, 256, 0, stream>>>(kvbuf, kvbf);
    k_attn_wo_ln1<<<512, 256, 0, stream>>>(bufQ, kvbf, kvbuf, Wo_t, pbuf,
                                           d_in[0], flag, bufX1);
    k_ff_ln2<<<512, 256, 0, stream>>>(bufX1, W1_t, W2_t, pbuf, flag, d_out);
}

// Round 9
// 364.585 us; speedup vs baseline: 1.2074x; 1.2074x over previous
//
#include <hip/hip_runtime.h>
#include <hip/hip_bf16.h>
#include <math.h>

#define NTOK   65536
#define L_SEQ  16384

typedef __bf16 bf16_t;
typedef bf16_t bf16x8 __attribute__((ext_vector_type(8)));
typedef bf16_t bf16x4 __attribute__((ext_vector_type(4)));
typedef float  f32x4  __attribute__((ext_vector_type(4)));

__device__ inline float phi_f(float x) { return x > 0.f ? x + 1.f : __expf(x); }

__device__ inline float quad_sum(float v) {
    v += __shfl_xor(v, 1);
    v += __shfl_xor(v, 2);
    v += __shfl_xor(v, 4);
    v += __shfl_xor(v, 8);
    return v;
}

__device__ inline float ld_any(const void* p, size_t i, int f32) {
    return f32 ? ((const float*)p)[i] : (float)((const bf16_t*)p)[i];
}

// async 16B global->LDS (direct-to-shared DMA; HW dest = wave-uniform base +
// lane*16 — callers below always pass lds ptrs of exactly that shape)
__device__ inline void async_copy16(const bf16_t* g, bf16_t* l) {
    __builtin_amdgcn_global_load_lds(
        (const __attribute__((address_space(1))) unsigned int*)g,
        (__attribute__((address_space(3))) unsigned int*)l, 16, 0, 0);
}

// Stage nslot 16-B units (8 bf16 each; nslot = elements/8) of a
// [rows][rowstride] bf16 slice into LDS with an XOR swizzle of the
// (1<<ulog2) units per row: phys j = u ^ (n & (U-1)).
__device__ inline void stage_swz(const bf16_t* __restrict__ g, bf16_t* lds,
                                 int tid, int nslot, int ulog2, int rowstride) {
    const int umask = (1 << ulog2) - 1;
    for (int s = tid; s < nslot; s += 256) {
        int n = s >> ulog2, j = s & umask;
        int u = j ^ (n & umask);
        async_copy16(g + (size_t)n * rowstride + u * 8, lds + (size_t)s * 8);
    }
}

__device__ inline bf16x8 rd_swz(const bf16_t* lds, int n, int u, int ulog2) {
    int j = u ^ (n & ((1 << ulog2) - 1));
    return *(const bf16x8*)&lds[(((size_t)n << ulog2) + j) * 8];
}

// ---- W2 chunk [256 n][32 k] packed as [128 rows][64 cols] so LDS rows span
// 128B = all 32 banks. Row r = n&127, slot u = (n>>7)*4 + k/8, phys = u^(r&7).
// Verified conflict-free in round 5.
__device__ inline void stage_w2ff(const bf16_t* __restrict__ W2_t, int ch,
                                  bf16_t* lds, int tid) {
    for (int S = tid; S < 1024; S += 256) {
        int r = S >> 3, phys = S & 7;
        int u = phys ^ (r & 7);
        int n = ((u >> 2) << 7) + r;
        int ks = u & 3;
        async_copy16(W2_t + (size_t)n * 1024 + ch * 32 + ks * 8, lds + (size_t)S * 8);
    }
}

__device__ inline bf16x8 rd_w2ff(const bf16_t* lds, int n, int quad) {
    int r = n & 127;
    int u = ((n >> 7) << 2) + quad;
    int phys = u ^ (r & 7);
    return *(const bf16x8*)&lds[(size_t)(r * 8 + phys) * 8];
}

// ---- [32 dim][128 tok] bf16 tile with 16B-unit XOR swizzle:
// element (r,c): unit u = c>>3, phys = u ^ (r&15), idx = r*128 + phys*8 + (c&7).
__device__ inline void hs_put(bf16_t* hs, int r, int c, bf16_t v) {
    int phys = (c >> 3) ^ (r & 15);
    hs[r * 128 + phys * 8 + (c & 7)] = v;
}
__device__ inline bf16x8 hs_get8(const bf16_t* hs, int r, int u) {
    int phys = u ^ (r & 15);
    return *(const bf16x8*)&hs[r * 128 + phys * 8];
}

// A-frags for one wave: row m, k = kk*32 + quad*8, kk=0..7 (K=256)
__device__ inline void ld_afrags(const bf16_t* __restrict__ tile, int row, int q8,
                                 bf16x8 a[8]) {
#pragma unroll
    for (int kk = 0; kk < 8; ++kk)
        a[kk] = *(const bf16x8*)&tile[(size_t)row * 256 + kk * 32 + q8];
}

// ------------------------------------------------- K-1: dtype probe
__global__ __launch_bounds__(256) void k_detect(const void* __restrict__ xraw,
                                                int* __restrict__ flag) {
    __shared__ int bad;
    if (threadIdx.x == 0) bad = 0;
    __syncthreads();
    const bf16_t* xb = (const bf16_t*)xraw;
    int mybad = 0;
#pragma unroll
    for (int j = 0; j < 16; ++j) {
        float v = fabsf((float)xb[threadIdx.x + 256 * j]);
        if (!(v <= 1000.f)) mybad = 1;
    }
    if (mybad) atomicOr(&bad, 1);
    __syncthreads();
    if (threadIdx.x == 0) *flag = bad;
}

// ------------------------------------------------- K0a: x -> canonical bf16
__global__ __launch_bounds__(256) void k_convert(const void* __restrict__ xraw,
                                                 const int* __restrict__ flag,
                                                 bf16_t* __restrict__ xbf) {
    const int f = *flag;
    size_t i = ((size_t)blockIdx.x * 256 + threadIdx.x) * 4;
    if (f) {
        f32x4 v = *(const f32x4*)((const float*)xraw + i);
        bf16x4 o;
#pragma unroll
        for (int j = 0; j < 4; ++j) o[j] = (bf16_t)v[j];
        *(bf16x4*)&xbf[i] = o;
    } else {
        *(bf16x4*)&xbf[i] = *(const bf16x4*)((const bf16_t*)xraw + i);
    }
}

// ------------------------------------------------- K0b: weight transpose + bias pack
__global__ __launch_bounds__(256) void k_prep(
    const void* __restrict__ Wq, const void* __restrict__ Wk,
    const void* __restrict__ Wv, const void* __restrict__ Wo,
    const void* __restrict__ W1, const void* __restrict__ W2,
    const void* __restrict__ bq, const void* __restrict__ bk,
    const void* __restrict__ bv, const void* __restrict__ bo,
    const void* __restrict__ b1, const void* __restrict__ b2,
    const void* __restrict__ g1, const void* __restrict__ be1,
    const void* __restrict__ g2, const void* __restrict__ be2,
    const int* __restrict__ flag,
    bf16_t* __restrict__ Wqkv_t, bf16_t* __restrict__ Wo_t,
    bf16_t* __restrict__ W1_t, bf16_t* __restrict__ W2_t,
    bf16_t* __restrict__ pbuf, float* __restrict__ kvbuf) {
    const int f = *flag;
    int idx = blockIdx.x * 256 + threadIdx.x;
    if (idx < 196608) {                       // Wqkv_t [768][256]
        int n = idx >> 8, k = idx & 255;
        float v;
        if (n < 256)      v = ld_any(Wq, k * 256 + n, f);
        else if (n < 512) v = ld_any(Wk, k * 256 + (n - 256), f);
        else              v = ld_any(Wv, k * 256 + (n - 512), f);
        Wqkv_t[idx] = (bf16_t)v;
    } else if (idx < 262144) {                // Wo_t [256][256]
        int i = idx - 196608; int n = i >> 8, k = i & 255;
        Wo_t[i] = (bf16_t)ld_any(Wo, k * 256 + n, f);
    } else if (idx < 524288) {                // W1_t [1024][256]
        int i = idx - 262144; int n = i >> 8, k = i & 255;
        W1_t[i] = (bf16_t)ld_any(W1, k * 1024 + n, f);
    } else if (idx < 786432) {                // W2_t [256][1024]
        int i = idx - 524288; int n = i >> 10, k = i & 1023;
        W2_t[i] = (bf16_t)ld_any(W2, k * 256 + n, f);
    } else if (idx < 820224) {                // KV state zero-init
        kvbuf[idx - 786432] = 0.f;
    } else if (idx < 823552) {                // bias/param pack
        int i = idx - 820224;
        float v;
        if (i < 256)        v = ld_any(bq, i, f);
        else if (i < 512)   v = ld_any(bk, i - 256, f);
        else if (i < 768)   v = ld_any(bv, i - 512, f);
        else if (i < 1024)  v = ld_any(bo, i - 768, f);
        else if (i < 2048)  v = ld_any(b1, i - 1024, f);
        else if (i < 2304)  v = ld_any(b2, i - 2048, f);
        else if (i < 2560)  v = ld_any(g1, i - 2304, f);
        else if (i < 2816)  v = ld_any(be1, i - 2560, f);
        else if (i < 3072)  v = ld_any(g2, i - 2816, f);
        else                v = ld_any(be2, i - 3072, f);
        pbuf[i] = (bf16_t)v;
    }
}

// ------------------------------------------------- K1: Q GEMM + phi (Q only)
// grid (512, 2): M=128, N=128 per block.
__global__ __launch_bounds__(256, 3) void k_qkv(
    const bf16_t* __restrict__ x, const bf16_t* __restrict__ Wqkv_t,
    const bf16_t* __restrict__ pbuf, bf16_t* __restrict__ q_phi) {
    const int mt = blockIdx.x, nt = blockIdx.y;
    const int tid = threadIdx.x, wave = tid >> 6, lane = tid & 63;
    const int l15 = lane & 15, quad = lane >> 4, q8 = quad * 8;
    __shared__ __align__(16) bf16_t bs[128 * 256];
    const int m0 = mt * 128;
    bf16x8 a[2][8];
    ld_afrags(x + (size_t)m0 * 256,        wave * 16 + l15, q8, a[0]);
    ld_afrags(x + (size_t)(m0 + 64) * 256, wave * 16 + l15, q8, a[1]);
    stage_swz(Wqkv_t + (size_t)nt * 128 * 256, bs, tid, 4096, 5, 256);
    __syncthreads();
    f32x4 acc[2][8] = {};
#pragma unroll
    for (int kk = 0; kk < 8; ++kk) {
#pragma unroll
        for (int s = 0; s < 8; ++s) {
            bf16x8 b = rd_swz(bs, s * 16 + l15, kk * 4 + quad, 5);
            acc[0][s] = __builtin_amdgcn_mfma_f32_16x16x32_bf16(a[0][kk], b, acc[0][s], 0, 0, 0);
            acc[1][s] = __builtin_amdgcn_mfma_f32_16x16x32_bf16(a[1][kk], b, acc[1][s], 0, 0, 0);
        }
    }
#pragma unroll
    for (int s = 0; s < 8; ++s) {
        int ng = nt * 128 + s * 16 + l15;      // 0..255: always Q
        float bias = (float)pbuf[ng];
#pragma unroll
        for (int mm = 0; mm < 2; ++mm) {
#pragma unroll
            for (int r = 0; r < 4; ++r) {
                int m = m0 + mm * 64 + wave * 16 + quad * 4 + r;
                q_phi[(size_t)m * 256 + ng] = (bf16_t)phi_f(acc[mm][s][r] + bias);
            }
        }
    }
}

// ------------------------------------------------- K2: fused K/V + kv partials
// Round 9: atomicAdd removed. Round-8 PMC: k_kv 131us, MfmaUtil 5%, WRITE_SIZE
// 80MB (~5x payload) -- 4.3M device-scope f32 atomics onto the same 33KB
// region serialized the chip. Now each block writes its own 1056-f32 partial
// per head (plain f32x4 stores, zero contention) into kvpart[bh][slab][1056];
// ksum partials get an in-LDS cross-wave reduce first. k_kvred sums slabs.
__global__ __launch_bounds__(256, 4) void k_kv(
    const bf16_t* __restrict__ x, const bf16_t* __restrict__ Wqkv_t,
    const bf16_t* __restrict__ pbuf, float* __restrict__ kvpart) {
    const int mt = blockIdx.x, hg = blockIdx.y;
    const int tid = threadIdx.x, wave = tid >> 6, lane = tid & 63;
    const int l15 = lane & 15, quad = lane >> 4, q8 = quad * 8;
    __shared__ __align__(16) bf16_t stg[8192];     // 32 cols x 256 K staging
    __shared__ __align__(16) bf16_t hsK[4096];     // [32 d][128 tok] swizzled
    __shared__ __align__(16) bf16_t hsV[4096];     // [32 e][128 tok] swizzled
    __shared__ float ksred[4][32];                 // per-wave ksum partials
    const int m0 = mt * 128;
    const int b = m0 >> 14;
    bf16x8 a[2][8];
    ld_afrags(x + (size_t)m0 * 256,        wave * 16 + l15, q8, a[0]);
    ld_afrags(x + (size_t)(m0 + 64) * 256, wave * 16 + l15, q8, a[1]);
    const int td = wave >> 1, te = wave & 1;       // this wave's kv 16x16 tile
    for (int h4 = 0; h4 < 4; ++h4) {
        const int head = hg * 4 + h4;
        float* dst = kvpart + ((size_t)(b * 8 + head) * 128 + (mt & 127)) * 1056;
        // ---------------- K phase ----------------
        stage_swz(Wqkv_t + (size_t)(256 + head * 32) * 256, stg, tid, 1024, 5, 256);
        __syncthreads();                            // stg ready; hsK/V + ksred free
        {
            f32x4 acck[2][2] = {};
#pragma unroll
            for (int kk = 0; kk < 8; ++kk) {
#pragma unroll
                for (int s = 0; s < 2; ++s) {
                    bf16x8 bb = rd_swz(stg, s * 16 + l15, kk * 4 + quad, 5);
                    acck[0][s] = __builtin_amdgcn_mfma_f32_16x16x32_bf16(a[0][kk], bb, acck[0][s], 0, 0, 0);
                    acck[1][s] = __builtin_amdgcn_mfma_f32_16x16x32_bf16(a[1][kk], bb, acck[1][s], 0, 0, 0);
                }
            }
#pragma unroll
            for (int s = 0; s < 2; ++s) {
                float bias = (float)pbuf[256 + head * 32 + s * 16 + l15];
                float kst = 0.f;
#pragma unroll
                for (int mm = 0; mm < 2; ++mm) {
#pragma unroll
                    for (int r = 0; r < 4; ++r) {
                        float v = phi_f(acck[mm][s][r] + bias);
                        kst += v;
                        int c = mm * 64 + wave * 16 + quad * 4 + r;   // token idx
                        hs_put(hsK, s * 16 + l15, c, (bf16_t)v);
                    }
                }
                kst += __shfl_xor(kst, 16);          // sum across quads
                kst += __shfl_xor(kst, 32);
                if (quad == 0) ksred[wave][s * 16 + l15] = kst;
            }
        }
        __syncthreads();                            // stg(K) consumed; ksred written
        // ---------------- V phase ----------------
        stage_swz(Wqkv_t + (size_t)(512 + head * 32) * 256, stg, tid, 1024, 5, 256);
        __syncthreads();                            // stg ready
        {
            f32x4 accv[2][2] = {};
#pragma unroll
            for (int kk = 0; kk < 8; ++kk) {
#pragma unroll
                for (int s = 0; s < 2; ++s) {
                    bf16x8 bb = rd_swz(stg, s * 16 + l15, kk * 4 + quad, 5);
                    accv[0][s] = __builtin_amdgcn_mfma_f32_16x16x32_bf16(a[0][kk], bb, accv[0][s], 0, 0, 0);
                    accv[1][s] = __builtin_amdgcn_mfma_f32_16x16x32_bf16(a[1][kk], bb, accv[1][s], 0, 0, 0);
                }
            }
#pragma unroll
            for (int s = 0; s < 2; ++s) {
                float bias = (float)pbuf[512 + head * 32 + s * 16 + l15];
#pragma unroll
                for (int mm = 0; mm < 2; ++mm) {
#pragma unroll
                    for (int r = 0; r < 4; ++r) {
                        int c = mm * 64 + wave * 16 + quad * 4 + r;   // token idx
                        hs_put(hsV, s * 16 + l15, c, (bf16_t)(accv[mm][s][r] + bias));
                    }
                }
            }
        }
        __syncthreads();                            // hsK + hsV + ksred complete
        // ---------------- kv contraction: D[d][e] = sum_tok K^T V -------------
        {
            f32x4 kvacc = {};
#pragma unroll
            for (int kk = 0; kk < 4; ++kk) {        // K = 128 tokens
                bf16x8 ak = hs_get8(hsK, td * 16 + l15, kk * 4 + quad);
                bf16x8 bv = hs_get8(hsV, te * 16 + l15, kk * 4 + quad);
                kvacc = __builtin_amdgcn_mfma_f32_16x16x32_bf16(ak, bv, kvacc, 0, 0, 0);
            }
            // C rows quad*4+r are consecutive d at fixed e -> one f32x4 store
            int e = te * 16 + l15;
            *(f32x4*)&dst[e * 32 + td * 16 + quad * 4] = kvacc;
        }
        if (tid < 32)                               // cross-wave ksum reduce
            dst[1024 + tid] = ksred[0][tid] + ksred[1][tid] + ksred[2][tid] + ksred[3][tid];
        // next head's first __syncthreads orders hsK/hsV/ksred overwrite
    }
}

// ------------------------------------------------- K2b: slab-partial reduction
// grid (32 bh, 5 idx-groups): sums 128 slab partials per (bh, idx); writes
// kvbuf f32 and (for the kv region) kvbf bf16 — absorbs the old k_kvprep.
__global__ __launch_bounds__(256) void k_kvred(const float* __restrict__ kvpart,
                                               float* __restrict__ kvbuf,
                                               bf16_t* __restrict__ kvbf) {
    const int bh = blockIdx.x;
    const int idx = blockIdx.y * 256 + threadIdx.x;
    if (idx >= 1056) return;
    const float* p = kvpart + (size_t)bh * 128 * 1056 + idx;
    float s = 0.f;
#pragma unroll 4
    for (int sl = 0; sl < 128; ++sl) s += p[(size_t)sl * 1056];
    kvbuf[(size_t)bh * 1056 + idx] = s;
    if (idx < 1024) kvbf[(size_t)bh * 1024 + idx] = (bf16_t)s;
}

// ------------------------------------------------- K3+K4 fused: attention
// apply (q_phi @ kv * z) + @Wo + x residual + LN1. M=128 per block.
__global__ __launch_bounds__(256, 2) void k_attn_wo_ln1(
    const bf16_t* __restrict__ q_phi, const bf16_t* __restrict__ kvbf,
    const float* __restrict__ kvbuf, const bf16_t* __restrict__ Wo_t,
    const bf16_t* __restrict__ pbuf, const void* __restrict__ xraw,
    const int* __restrict__ flag, bf16_t* __restrict__ x1) {
    const int f = *flag;
    const int mt = blockIdx.x;
    const int tid = threadIdx.x, wave = tid >> 6, lane = tid & 63;
    const int l15 = lane & 15, quad = lane >> 4, q8 = quad * 8;
    __shared__ __align__(16) bf16_t sm0[8192];         // Wo chunk (nc even), 16KB
    __shared__ __align__(16) bf16_t sm1[16896];        // hs, then Wo chunk (nc odd)
    const int m0 = mt * 128;
    const int b = m0 >> 14;                            // batch (128-row blocks never straddle)
    stage_swz(Wo_t, sm0, tid, 1024, 5, 256);           // async chunk0 (32 rows)
    // ---------------- attention phase (wave-local, no barrier) ----------------
    bf16_t* hs = sm1 + wave * (16 * 264);              // [16 rows][264 cols]
    const bf16_t* kvb = kvbf + (size_t)b * 8192;       // 8 heads * 1024 bf16
    const float*  ksb = kvbuf + (size_t)b * 8448;      // 8 heads * 1056 f32
    bf16x8 a2[2][8];
#pragma unroll
    for (int mm = 0; mm < 2; ++mm) {
        bf16x8 a[8];
        ld_afrags(q_phi + (size_t)(m0 + mm * 64) * 256, wave * 16 + l15, q8, a);
#pragma unroll
        for (int h = 0; h < 8; ++h) {
            // denominator: q[m=l15][h*32 + quad*8+j] . ksum
            f32x4 ks0 = *(const f32x4*)&ksb[h * 1056 + 1024 + q8];
            f32x4 ks1 = *(const f32x4*)&ksb[h * 1056 + 1024 + q8 + 4];
            float den = 0.f;
#pragma unroll
            for (int j = 0; j < 4; ++j) den += (float)a[h][j] * ks0[j];
#pragma unroll
            for (int j = 0; j < 4; ++j) den += (float)a[h][4 + j] * ks1[j];
            den += __shfl_xor(den, 16);                // reduce across quads
            den += __shfl_xor(den, 32);
            float z = 1.f / (den + 1e-6f);             // z for row = l15
            float zr[4];
#pragma unroll
            for (int r = 0; r < 4; ++r) zr[r] = __shfl(z, quad * 4 + r, 16);
            // numerator: B[k=d][n=e] = kv[d][e], e-major -> contiguous frag
            bf16x8 b0 = *(const bf16x8*)&kvb[h * 1024 + l15 * 32 + q8];
            bf16x8 b1 = *(const bf16x8*)&kvb[h * 1024 + (16 + l15) * 32 + q8];
            f32x4 at0 = {}, at1 = {};
            at0 = __builtin_amdgcn_mfma_f32_16x16x32_bf16(a[h], b0, at0, 0, 0, 0);
            at1 = __builtin_amdgcn_mfma_f32_16x16x32_bf16(a[h], b1, at1, 0, 0, 0);
#pragma unroll
            for (int r = 0; r < 4; ++r) {              // C-layout: row=quad*4+r, col=l15
                hs[(quad * 4 + r) * 264 + h * 32 + l15]      = (bf16_t)(at0[r] * zr[r]);
                hs[(quad * 4 + r) * 264 + h * 32 + 16 + l15] = (bf16_t)(at1[r] * zr[r]);
            }
        }
        // wave-local C->A layout round-trip (in-order DS pipe within wave)
#pragma unroll
        for (int kk = 0; kk < 8; ++kk)
            a2[mm][kk] = *(const bf16x8*)&hs[l15 * 264 + kk * 32 + q8];
    }
    __syncthreads();       // sm0 chunk0 staged; all waves done with hs (sm1)
    // ---------------- Wo GEMM, 8 chunks of 32 cols, ping-pong sm0/sm1 --------
    f32x4 acc[2][16] = {};
    for (int nc = 0; nc < 8; ++nc) {
        if (nc < 7) stage_swz(Wo_t + (size_t)(nc + 1) * 32 * 256,
                              (nc & 1) ? sm0 : sm1, tid, 1024, 5, 256);
        const bf16_t* buf = (nc & 1) ? sm1 : sm0;
#pragma unroll
        for (int kk = 0; kk < 8; ++kk) {
#pragma unroll
            for (int s = 0; s < 2; ++s) {
                bf16x8 bb = rd_swz(buf, s * 16 + l15, kk * 4 + quad, 5);
                acc[0][nc * 2 + s] = __builtin_amdgcn_mfma_f32_16x16x32_bf16(a2[0][kk], bb, acc[0][nc * 2 + s], 0, 0, 0);
                acc[1][nc * 2 + s] = __builtin_amdgcn_mfma_f32_16x16x32_bf16(a2[1][kk], bb, acc[1][nc * 2 + s], 0, 0, 0);
            }
        }
        __syncthreads();   // publishes next chunk, protects current from overwrite
    }
    // ---------------- epilogue: bias + x residual + LN1 (per m-subtile) ------
#pragma unroll
    for (int mm = 0; mm < 2; ++mm) {
        float s1[4] = {}, s2[4] = {};
#pragma unroll
        for (int s = 0; s < 16; ++s) {
            int n = s * 16 + l15;
            float bias = (float)pbuf[768 + n];
#pragma unroll
            for (int r = 0; r < 4; ++r) {
                int m = m0 + mm * 64 + wave * 16 + quad * 4 + r;
                float val = acc[mm][s][r] + bias + ld_any(xraw, (size_t)m * 256 + n, f);
                acc[mm][s][r] = val;
                s1[r] += val; s2[r] += val * val;
            }
        }
#pragma unroll
        for (int r = 0; r < 4; ++r) {
            float ts = quad_sum(s1[r]), ts2 = quad_sum(s2[r]);
            float mu = ts * (1.f / 256.f);
            float rs = rsqrtf(ts2 * (1.f / 256.f) - mu * mu + 1e-5f);
            s1[r] = mu; s2[r] = rs;
        }
#pragma unroll
        for (int s = 0; s < 16; ++s) {
            int n = s * 16 + l15;
            float gn = (float)pbuf[2304 + n], bn = (float)pbuf[2560 + n];
#pragma unroll
            for (int r = 0; r < 4; ++r) {
                int m = m0 + mm * 64 + wave * 16 + quad * 4 + r;
                x1[(size_t)m * 256 + n] = (bf16_t)((acc[mm][s][r] - s1[r]) * s2[r] * gn + bn);
            }
        }
    }
}

// ------------------------------------------------- K5: fused FFN + LN2
// M=128 per block (512 blocks), double-buffer + 1 barrier/chunk, conflict-free
// w2ff pack. (Round-6 verified: ~115us, LDS-BW-bound.) Unchanged.
__global__ __launch_bounds__(256, 2) void k_ff_ln2(
    const bf16_t* __restrict__ x1, const bf16_t* __restrict__ W1_t,
    const bf16_t* __restrict__ W2_t, const bf16_t* __restrict__ pbuf,
    const int* __restrict__ flag, void* __restrict__ out) {
    const int f32o = *flag;
    const int mt = blockIdx.x;                        // 512 blocks, 128 rows each
    const int tid = threadIdx.x, wave = tid >> 6, lane = tid & 63;
    const int l15 = lane & 15, quad = lane >> 4, q8 = quad * 8;
    __shared__ __align__(16) bf16_t w1s[2][8192];     // 32 ff-rows x 256 K each
    __shared__ __align__(16) bf16_t w2s[2][8192];     // [128][64] packed chunk
    __shared__ __align__(16) bf16_t hs[4][2][16][40]; // wave x m-subtile h buf
    const int m0 = mt * 128 + wave * 32;              // wave's first row
    bf16x8 a[2][8];
    ld_afrags(x1 + (size_t)m0 * 256, l15,      q8, a[0]);
    ld_afrags(x1 + (size_t)m0 * 256, 16 + l15, q8, a[1]);
    stage_swz(W1_t, w1s[0], tid, 1024, 5, 256);
    stage_w2ff(W2_t, 0, w2s[0], tid);
    __syncthreads();
    f32x4 acc[2][16] = {};
    for (int ch = 0; ch < 32; ++ch) {
        const int cur = ch & 1;
        // prefetch next chunk into the idle buffers (latency hides under MFMAs)
        if (ch < 31) {
            stage_swz(W1_t + (size_t)(ch + 1) * 32 * 256, w1s[cur ^ 1], tid, 1024, 5, 256);
            stage_w2ff(W2_t, ch + 1, w2s[cur ^ 1], tid);
        }
        // step a: h = relu(x1 @ W1_chunk + b1), 32 ff-cols, 2 m-subtiles
        f32x4 h0[2] = {}, h1[2] = {};
#pragma unroll
        for (int kk = 0; kk < 8; ++kk) {
#pragma unroll
            for (int s = 0; s < 2; ++s) {
                bf16x8 b = rd_swz(w1s[cur], s * 16 + l15, kk * 4 + quad, 5);
                h0[s] = __builtin_amdgcn_mfma_f32_16x16x32_bf16(a[0][kk], b, h0[s], 0, 0, 0);
                h1[s] = __builtin_amdgcn_mfma_f32_16x16x32_bf16(a[1][kk], b, h1[s], 0, 0, 0);
            }
        }
#pragma unroll
        for (int s = 0; s < 2; ++s) {
            float bias = (float)pbuf[1024 + ch * 32 + s * 16 + l15];
#pragma unroll
            for (int r = 0; r < 4; ++r) {
                float v0 = h0[s][r] + bias;
                float v1 = h1[s][r] + bias;
                hs[wave][0][quad * 4 + r][s * 16 + l15] = (bf16_t)(v0 > 0.f ? v0 : 0.f);
                hs[wave][1][quad * 4 + r][s * 16 + l15] = (bf16_t)(v1 > 0.f ? v1 : 0.f);
            }
        }
        // wave-local C->A layout round-trip (in-order DS pipe within wave)
        bf16x8 a2_0 = *(const bf16x8*)&hs[wave][0][l15][q8];
        bf16x8 a2_1 = *(const bf16x8*)&hs[wave][1][l15][q8];
        // step b: out += h_chunk @ W2_chunk (B-frag shared across m-subtiles)
#pragma unroll
        for (int s = 0; s < 16; ++s) {
            bf16x8 b0 = rd_w2ff(w2s[cur], s * 16 + l15, quad);
            acc[0][s] = __builtin_amdgcn_mfma_f32_16x16x32_bf16(a2_0, b0, acc[0][s], 0, 0, 0);
            acc[1][s] = __builtin_amdgcn_mfma_f32_16x16x32_bf16(a2_1, b0, acc[1][s], 0, 0, 0);
        }
        __syncthreads();   // next-chunk stages complete; cur buffers reusable
    }
    // epilogue: + b2 + x1 residual, LN2, dual-dtype store (per m-subtile)
#pragma unroll
    for (int mm = 0; mm < 2; ++mm) {
        float s1[4] = {}, s2[4] = {};
#pragma unroll
        for (int s = 0; s < 16; ++s) {
            int n = s * 16 + l15;
            float bias = (float)pbuf[2048 + n];
#pragma unroll
            for (int r = 0; r < 4; ++r) {
                int m = m0 + mm * 16 + quad * 4 + r;
                float val = acc[mm][s][r] + bias + (float)x1[(size_t)m * 256 + n];
                acc[mm][s][r] = val;
                s1[r] += val; s2[r] += val * val;
            }
        }
#pragma unroll
        for (int r = 0; r < 4; ++r) {
            float ts = quad_sum(s1[r]), ts2 = quad_sum(s2[r]);
            float mu = ts * (1.f / 256.f);
            float rs = rsqrtf(ts2 * (1.f / 256.f) - mu * mu + 1e-5f);
            s1[r] = mu; s2[r] = rs;
        }
#pragma unroll
        for (int s = 0; s < 16; ++s) {
            int n = s * 16 + l15;
            float gn = (float)pbuf[2816 + n], bn = (float)pbuf[3072 + n];
#pragma unroll
            for (int r = 0; r < 4; ++r) {
                int m = m0 + mm * 16 + quad * 4 + r;
                float val = (acc[mm][s][r] - s1[r]) * s2[r] * gn + bn;
                if (f32o) ((float*)out)[(size_t)m * 256 + n] = val;
                else      ((bf16_t*)out)[(size_t)m * 256 + n] = (bf16_t)val;
            }
        }
    }
}

// ------------------------------------------------- launch
extern "C" void kernel_launch(void* const* d_in, const int* in_sizes, int n_in,
                              void* d_out, int out_size, void* d_ws, size_t ws_size,
                              hipStream_t stream) {
    char* ws = (char*)d_ws;
    int*    flag   = (int*)ws;                              // 4 B (256 reserved)
    bf16_t* xbf    = (bf16_t*)(ws + 256);                   // 16.7M elems
    bf16_t* Wqkv_t = (bf16_t*)(ws + 33554688);              // 196608
    bf16_t* Wo_t   = (bf16_t*)(ws + 33947904);              // 65536
    bf16_t* W1_t   = (bf16_t*)(ws + 34078976);              // 262144
    bf16_t* W2_t   = (bf16_t*)(ws + 34603264);              // 262144
    bf16_t* pbuf   = (bf16_t*)(ws + 35127552);              // 3328
    float*  kvbuf  = (float*)(ws + 35134208);               // 33792 f32
    bf16_t* bufQ   = (bf16_t*)(ws + 35269376);              // 16.7M elems
    bf16_t* kvbf   = bufQ + (size_t)NTOK * 256;             // 64KB (old bufK slot)
    float*  kvpart = (float*)(ws + 35269376 + 2u * NTOK * 256 + 65536); // 17.3MB
    bf16_t* bufX1  = bufQ;    // Q read + overwritten row-local in k_attn_wo_ln1

    k_detect<<<1, 256, 0, stream>>>(d_in[0], flag);
    k_convert<<<16384, 256, 0, stream>>>(d_in[0], flag, xbf);
    k_prep<<<3217, 256, 0, stream>>>(d_in[1], d_in[3], d_in[5], d_in[7],
                                     d_in[9], d_in[11],
                                     d_in[2], d_in[4], d_in[6], d_in[8],
                                     d_in[10], d_in[12],
                                     d_in[13], d_in[14], d_in[15], d_in[16],
                                     flag, Wqkv_t, Wo_t, W1_t, W2_t, pbuf, kvbuf);
    k_qkv<<<dim3(512, 2), 256, 0, stream>>>(xbf, Wqkv_t, pbuf, bufQ);
    k_kv<<<dim3(512, 2), 256, 0, stream>>>(xbf, Wqkv_t, pbuf, kvpart);
    k_kvred<<<dim3(32, 5), 256, 0, stream>>>(kvpart, kvbuf, kvbf);
    k_attn_wo_ln1<<<512, 256, 0, stream>>>(bufQ, kvbf, kvbuf, Wo_t, pbuf,
                                           d_in[0], flag, bufX1);
    k_ff_ln2<<<512, 256, 0, stream>>>(bufX1, W1_t, W2_t, pbuf, flag, d_out);
}